// Round 1
// baseline (5956.848 us; speedup 1.0000x reference)
//
#include <hip/hip_runtime.h>

#define N_NODES 50000
#define N_EDGES 1600000
#define NB 128
#define DD 64

__device__ __forceinline__ int lower_bound_i(const int* __restrict__ a, int n, int v) {
    int lo = 0, hi = n;
    while (lo < hi) {
        int mid = (lo + hi) >> 1;
        if (a[mid] < v) lo = mid + 1; else hi = mid;
    }
    return lo;
}

// h += vn[batch]; out = (first ? h : out + h); optionally agg = (1+eps[l])*h
// grid: N*16 threads (float4 per thread)
__global__ __launch_bounds__(256) void k_pre(
    float* __restrict__ h, const float* __restrict__ vn,
    const int* __restrict__ batch_id, float* __restrict__ out,
    float* __restrict__ agg, const float* __restrict__ eps, int l, int first) {
    int t = blockIdx.x * 256 + threadIdx.x;   // 0 .. N*16-1
    int i = t >> 4, q = t & 15;
    float4 hv = ((const float4*)h)[t];
    float4 vv = ((const float4*)vn)[(batch_id[i] << 4) + q];
    float4 v;
    v.x = hv.x + vv.x; v.y = hv.y + vv.y; v.z = hv.z + vv.z; v.w = hv.w + vv.w;
    ((float4*)h)[t] = v;
    if (first) {
        ((float4*)out)[t] = v;
    } else {
        float4 o = ((float4*)out)[t];
        o.x += v.x; o.y += v.y; o.z += v.z; o.w += v.w;
        ((float4*)out)[t] = o;
    }
    if (agg != nullptr) {
        float s = 1.0f + eps[l];
        float4 a;
        a.x = s * v.x; a.y = s * v.y; a.z = s * v.z; a.w = s * v.w;
        ((float4*)agg)[t] = a;
    }
}

// pooled[b] = sum_{i: batch_id[i]==b} h[i] + vn[b]   (batch_id is sorted)
// grid: NB blocks x 64 threads
__global__ __launch_bounds__(64) void k_pool(
    const float* __restrict__ h, const int* __restrict__ batch_id,
    const float* __restrict__ vn, float* __restrict__ pooled, int n) {
    int b = blockIdx.x;
    int c = threadIdx.x;
    int start = lower_bound_i(batch_id, n, b);
    int end   = lower_bound_i(batch_id, n, b + 1);
    float s = 0.0f;
    for (int i = start; i < end; ++i)
        s += h[(size_t)i * 64 + c];
    pooled[b * 64 + c] = s + vn[b * 64 + c];
}

// agg[dst[e]] += relu(h[src[e]])  — one float4 per thread, grid = E*16
__global__ __launch_bounds__(256) void k_edge(
    const float* __restrict__ h, const int* __restrict__ src,
    const int* __restrict__ dst, float* __restrict__ agg) {
    int t = blockIdx.x * 256 + threadIdx.x;   // 0 .. E*16-1
    int e = t >> 4, q = t & 15;
    int s = src[e];
    int d = dst[e];
    float4 hv = ((const float4*)h)[(size_t)s * 16 + q];
    float* base = agg + (size_t)d * 64 + q * 4;
    if (hv.x > 0.0f) atomicAdd(base + 0, hv.x);
    if (hv.y > 0.0f) atomicAdd(base + 1, hv.y);
    if (hv.z > 0.0f) atomicAdd(base + 2, hv.z);
    if (hv.w > 0.0f) atomicAdd(base + 3, hv.w);
}

// vn[b][c] = vn_emb[c]  — 8192 threads
__global__ __launch_bounds__(256) void k_vn_init(
    const float* __restrict__ vn_emb, float* __restrict__ vn) {
    int t = blockIdx.x * 256 + threadIdx.x;
    vn[t] = vn_emb[t & 63];
}

// out = op(in @ W + bias); mode 0: bias only; mode 1: bias + BN(g,b,m,v) + relu
// in:[n,64] W:[64,64] — block handles 64 rows, 256 threads, 4 rows x 4 cols each
__global__ __launch_bounds__(256) void k_gemm(
    const float* __restrict__ in, const float* __restrict__ W,
    const float* __restrict__ bias, const float* __restrict__ bn_g,
    const float* __restrict__ bn_b, const float* __restrict__ bn_m,
    const float* __restrict__ bn_v, float* __restrict__ out, int n, int mode) {
    __shared__ float sW[64 * 64];
    __shared__ float sIn[64 * 68];   // padded stride 68 to dodge bank conflicts
    int tid = threadIdx.x;
    int row0 = blockIdx.x * 64;

    const float4* W4 = (const float4*)W;
    float4* sW4 = (float4*)sW;
#pragma unroll
    for (int i = 0; i < 4; ++i) sW4[tid + 256 * i] = W4[tid + 256 * i];

    const float4* in4 = (const float4*)in;
#pragma unroll
    for (int i = 0; i < 4; ++i) {
        int idx = tid + 256 * i;
        int r = idx >> 4, j = idx & 15;
        float4 val = make_float4(0.f, 0.f, 0.f, 0.f);
        if (row0 + r < n) val = in4[(size_t)(row0 + r) * 16 + j];
        ((float4*)sIn)[r * 17 + j] = val;
    }
    __syncthreads();

    int c4 = (tid & 15) * 4;
    int rl = (tid >> 4) * 4;
    float acc[4][4] = {{0.f}};
#pragma unroll 8
    for (int k = 0; k < 64; ++k) {
        float4 wv = *(const float4*)(sW + k * 64 + c4);
        float a0 = sIn[(rl + 0) * 68 + k];
        float a1 = sIn[(rl + 1) * 68 + k];
        float a2 = sIn[(rl + 2) * 68 + k];
        float a3 = sIn[(rl + 3) * 68 + k];
        acc[0][0] += a0 * wv.x; acc[0][1] += a0 * wv.y; acc[0][2] += a0 * wv.z; acc[0][3] += a0 * wv.w;
        acc[1][0] += a1 * wv.x; acc[1][1] += a1 * wv.y; acc[1][2] += a1 * wv.z; acc[1][3] += a1 * wv.w;
        acc[2][0] += a2 * wv.x; acc[2][1] += a2 * wv.y; acc[2][2] += a2 * wv.z; acc[2][3] += a2 * wv.w;
        acc[3][0] += a3 * wv.x; acc[3][1] += a3 * wv.y; acc[3][2] += a3 * wv.z; acc[3][3] += a3 * wv.w;
    }

    // epilogue: fold bias into BN shift
    float scl[4], shf[4];
#pragma unroll
    for (int j = 0; j < 4; ++j) {
        int c = c4 + j;
        float bsum = bias ? bias[c] : 0.0f;
        if (mode == 1) {
            float sc = bn_g[c] * rsqrtf(bn_v[c] + 1e-5f);
            scl[j] = sc;
            shf[j] = bn_b[c] - bn_m[c] * sc + bsum * sc;
        } else {
            scl[j] = 1.0f;
            shf[j] = bsum;
        }
    }
#pragma unroll
    for (int r = 0; r < 4; ++r) {
        int row = row0 + rl + r;
        if (row < n) {
            float4 o;
            o.x = acc[r][0] * scl[0] + shf[0];
            o.y = acc[r][1] * scl[1] + shf[1];
            o.z = acc[r][2] * scl[2] + shf[2];
            o.w = acc[r][3] * scl[3] + shf[3];
            if (mode == 1) {
                o.x = fmaxf(o.x, 0.f); o.y = fmaxf(o.y, 0.f);
                o.z = fmaxf(o.z, 0.f); o.w = fmaxf(o.w, 0.f);
            }
            *(float4*)(out + (size_t)row * 64 + c4) = o;
        }
    }
}

extern "C" void kernel_launch(void* const* d_in, const int* in_sizes, int n_in,
                              void* d_out, int out_size, void* d_ws, size_t ws_size,
                              hipStream_t stream) {
    const float* x      = (const float*)d_in[0];
    const float* lin_W  = (const float*)d_in[1];
    const float* lin_b  = (const float*)d_in[2];
    const float* eps    = (const float*)d_in[3];
    const float* gin_W1 = (const float*)d_in[4];
    const float* gin_b1 = (const float*)d_in[5];
    const float* gbn_g  = (const float*)d_in[6];
    const float* gbn_b  = (const float*)d_in[7];
    const float* gbn_m  = (const float*)d_in[8];
    const float* gbn_v  = (const float*)d_in[9];
    const float* gin_W2 = (const float*)d_in[10];
    const float* gin_b2 = (const float*)d_in[11];
    const float* bn_g   = (const float*)d_in[12];
    const float* bn_b   = (const float*)d_in[13];
    const float* bn_m   = (const float*)d_in[14];
    const float* bn_v   = (const float*)d_in[15];
    const float* vn_emb = (const float*)d_in[16];
    const float* vn_W1  = (const float*)d_in[17];
    const float* vn_b1  = (const float*)d_in[18];
    const float* v1g    = (const float*)d_in[19];
    const float* v1b    = (const float*)d_in[20];
    const float* v1m    = (const float*)d_in[21];
    const float* v1v    = (const float*)d_in[22];
    const float* vn_W2  = (const float*)d_in[23];
    const float* vn_b2  = (const float*)d_in[24];
    const float* v2g    = (const float*)d_in[25];
    const float* v2b    = (const float*)d_in[26];
    const float* v2m    = (const float*)d_in[27];
    const float* v2v    = (const float*)d_in[28];
    const int* src      = (const int*)d_in[29];
    const int* dst      = (const int*)d_in[30];
    const int* batch_id = (const int*)d_in[31];
    float* out = (float*)d_out;

    float* h      = (float*)d_ws;                      // N*64
    float* agg    = h   + (size_t)N_NODES * 64;        // N*64
    float* z1     = agg + (size_t)N_NODES * 64;        // N*64 (also reused as vt[128,64])
    float* vn     = z1  + (size_t)N_NODES * 64;        // B*64
    float* pooled = vn  + (size_t)NB * 64;             // B*64

    const int GB = (N_NODES + 63) / 64;                // 782
    const int PRE_BLOCKS  = N_NODES * 16 / 256;        // 3125 (exact)
    const int EDGE_BLOCKS = N_EDGES * 16 / 256;        // 100000 (exact)

    // input linear: h = x @ lin_W + lin_b
    k_gemm<<<GB, 256, 0, stream>>>(x, lin_W, lin_b, nullptr, nullptr, nullptr,
                                   nullptr, h, N_NODES, 0);
    // vn = broadcast(vn_emb)
    k_vn_init<<<32, 256, 0, stream>>>(vn_emb, vn);

    for (int l = 0; l < 4; ++l) {   // layer 4's GINConv output (h_list[5]) is never used
        // h += vn[batch]; out accumulate; agg = (1+eps)*h
        k_pre<<<PRE_BLOCKS, 256, 0, stream>>>(h, vn, batch_id, out, agg, eps, l, l == 0);
        // pooled = segment_sum(h, batch) + vn   (needs post-vn h, pre-overwrite)
        k_pool<<<NB, 64, 0, stream>>>(h, batch_id, vn, pooled, N_NODES);
        // agg += relu(h[src]) scattered to dst
        k_edge<<<EDGE_BLOCKS, 256, 0, stream>>>(h, src, dst, agg);
        // z1 = relu(BN1(agg @ W1 + b1))
        k_gemm<<<GB, 256, 0, stream>>>(agg, gin_W1 + l * 4096, gin_b1 + l * 64,
                                       gbn_g + l * 64, gbn_b + l * 64,
                                       gbn_m + l * 64, gbn_v + l * 64, z1, N_NODES, 1);
        // h = relu(BN2(z1 @ W2 + b2))   (relu applies for l=0..3)
        k_gemm<<<GB, 256, 0, stream>>>(z1, gin_W2 + l * 4096, gin_b2 + l * 64,
                                       bn_g + l * 64, bn_b + l * 64,
                                       bn_m + l * 64, bn_v + l * 64, h, N_NODES, 1);
        // vn MLP: vt = relu(BN(pooled @ vn_W1 + b1)); vn = relu(BN(vt @ vn_W2 + b2))
        k_gemm<<<2, 256, 0, stream>>>(pooled, vn_W1 + l * 4096, vn_b1 + l * 64,
                                      v1g + l * 64, v1b + l * 64,
                                      v1m + l * 64, v1v + l * 64, z1, NB, 1);
        k_gemm<<<2, 256, 0, stream>>>(z1, vn_W2 + l * 4096, vn_b2 + l * 64,
                                      v2g + l * 64, v2b + l * 64,
                                      v2m + l * 64, v2v + l * 64, vn, NB, 1);
    }
    // l = 4: only h += vn[batch]; out += h
    k_pre<<<PRE_BLOCKS, 256, 0, stream>>>(h, vn, batch_id, out, nullptr, eps, 4, 0);
}

// Round 2
// 1284.826 us; speedup vs baseline: 4.6363x; 4.6363x over previous
//
#include <hip/hip_runtime.h>

#define N_NODES 50000
#define N_EDGES 1600000
#define NB 128
#define DD 64

__device__ __forceinline__ int lower_bound_i(const int* __restrict__ a, int n, int v) {
    int lo = 0, hi = n;
    while (lo < hi) {
        int mid = (lo + hi) >> 1;
        if (a[mid] < v) lo = mid + 1; else hi = mid;
    }
    return lo;
}

// h += vn[batch]; out = (first ? h : out + h); optionally rbuf = relu(h)
// grid: N*16 threads (float4 per thread)
__global__ __launch_bounds__(256) void k_pre(
    float* __restrict__ h, const float* __restrict__ vn,
    const int* __restrict__ batch_id, float* __restrict__ out,
    float* __restrict__ rbuf, int first) {
    int t = blockIdx.x * 256 + threadIdx.x;   // 0 .. N*16-1
    int i = t >> 4, q = t & 15;
    float4 hv = ((const float4*)h)[t];
    float4 vv = ((const float4*)vn)[(batch_id[i] << 4) + q];
    float4 v;
    v.x = hv.x + vv.x; v.y = hv.y + vv.y; v.z = hv.z + vv.z; v.w = hv.w + vv.w;
    ((float4*)h)[t] = v;
    if (first) {
        ((float4*)out)[t] = v;
    } else {
        float4 o = ((float4*)out)[t];
        o.x += v.x; o.y += v.y; o.z += v.z; o.w += v.w;
        ((float4*)out)[t] = o;
    }
    if (rbuf != nullptr) {
        float4 r;
        r.x = fmaxf(v.x, 0.f); r.y = fmaxf(v.y, 0.f);
        r.z = fmaxf(v.z, 0.f); r.w = fmaxf(v.w, 0.f);
        ((float4*)rbuf)[t] = r;
    }
}

// pooled[b] = sum_{i: batch_id[i]==b} h[i] + vn[b]   (batch_id is sorted)
__global__ __launch_bounds__(64) void k_pool(
    const float* __restrict__ h, const int* __restrict__ batch_id,
    const float* __restrict__ vn, float* __restrict__ pooled, int n) {
    int b = blockIdx.x;
    int c = threadIdx.x;
    int start = lower_bound_i(batch_id, n, b);
    int end   = lower_bound_i(batch_id, n, b + 1);
    float s = 0.0f;
    for (int i = start; i < end; ++i)
        s += h[(size_t)i * 64 + c];
    pooled[b * 64 + c] = s + vn[b * 64 + c];
}

// ---- CSR build (per launch; edges are launch-constant) ----
__global__ __launch_bounds__(256) void k_hist(
    const int* __restrict__ dst, int* __restrict__ deg) {
    int e = blockIdx.x * 256 + threadIdx.x;
    atomicAdd(&deg[dst[e]], 1);
}

// single block, 1024 threads: exclusive scan of deg[0..N) -> row_ptr, cursor
__global__ __launch_bounds__(1024) void k_scan(
    const int* __restrict__ deg, int* __restrict__ row_ptr, int* __restrict__ cursor) {
    __shared__ int lsum[1024];
    const int CH = 49;   // 1024*49 = 50176 >= N
    int t = threadIdx.x;
    int begin = t * CH;
    int end = begin + CH; if (end > N_NODES) end = N_NODES;
    int s = 0;
    for (int i = begin; i < end && i >= begin; ++i) s += (begin < N_NODES) ? deg[i] : 0;
    lsum[t] = s;
    __syncthreads();
    // inclusive scan (read-before-write each step)
    for (int off = 1; off < 1024; off <<= 1) {
        int x = lsum[t];
        int y = (t >= off) ? lsum[t - off] : 0;
        __syncthreads();
        lsum[t] = x + y;
        __syncthreads();
    }
    int run = lsum[t] - s;   // exclusive prefix for this chunk
    for (int i = begin; i < end && begin < N_NODES; ++i) {
        row_ptr[i] = run; cursor[i] = run; run += deg[i];
    }
    if (t == 1023) row_ptr[N_NODES] = lsum[1023];
}

__global__ __launch_bounds__(256) void k_scatter(
    const int* __restrict__ src, const int* __restrict__ dst,
    int* __restrict__ cursor, int* __restrict__ csr_src) {
    int e = blockIdx.x * 256 + threadIdx.x;
    int pos = atomicAdd(&cursor[dst[e]], 1);
    csr_src[pos] = src[e];
}

// agg[d] = (1+eps[l])*h[d] + sum_{e in csr row d} rbuf[csr_src[e]]
// one wave (64 lanes = 64 channels) per dst node; 4 waves/block
__global__ __launch_bounds__(256) void k_agg(
    const float* __restrict__ h, const float* __restrict__ rbuf,
    const int* __restrict__ row_ptr, const int* __restrict__ csr_src,
    float* __restrict__ agg, const float* __restrict__ eps, int l) {
    int wave = threadIdx.x >> 6;
    int lane = threadIdx.x & 63;
    int node = blockIdx.x * 4 + wave;
    int start = row_ptr[node], end = row_ptr[node + 1];
    float acc = (1.0f + eps[l]) * h[(size_t)node * 64 + lane];
    for (int base = start; base < end; base += 64) {
        int e = base + lane;
        int s = (e < end) ? csr_src[e] : 0;
        int cnt = end - base; if (cnt > 64) cnt = 64;
        int j = 0;
        for (; j + 3 < cnt; j += 4) {
            int s0 = __shfl(s, j), s1 = __shfl(s, j + 1);
            int s2 = __shfl(s, j + 2), s3 = __shfl(s, j + 3);
            float v0 = rbuf[(size_t)s0 * 64 + lane];
            float v1 = rbuf[(size_t)s1 * 64 + lane];
            float v2 = rbuf[(size_t)s2 * 64 + lane];
            float v3 = rbuf[(size_t)s3 * 64 + lane];
            acc += (v0 + v1) + (v2 + v3);
        }
        for (; j < cnt; ++j) {
            int sj = __shfl(s, j);
            acc += rbuf[(size_t)sj * 64 + lane];
        }
    }
    agg[(size_t)node * 64 + lane] = acc;
}

// vn[b][c] = vn_emb[c]
__global__ __launch_bounds__(256) void k_vn_init(
    const float* __restrict__ vn_emb, float* __restrict__ vn) {
    int t = blockIdx.x * 256 + threadIdx.x;
    vn[t] = vn_emb[t & 63];
}

// out = op(in @ W + bias); mode 0: bias only; mode 1: bias + BN + relu
__global__ __launch_bounds__(256) void k_gemm(
    const float* __restrict__ in, const float* __restrict__ W,
    const float* __restrict__ bias, const float* __restrict__ bn_g,
    const float* __restrict__ bn_b, const float* __restrict__ bn_m,
    const float* __restrict__ bn_v, float* __restrict__ out, int n, int mode) {
    __shared__ float sW[64 * 64];
    __shared__ float sIn[64 * 68];
    int tid = threadIdx.x;
    int row0 = blockIdx.x * 64;

    const float4* W4 = (const float4*)W;
    float4* sW4 = (float4*)sW;
#pragma unroll
    for (int i = 0; i < 4; ++i) sW4[tid + 256 * i] = W4[tid + 256 * i];

    const float4* in4 = (const float4*)in;
#pragma unroll
    for (int i = 0; i < 4; ++i) {
        int idx = tid + 256 * i;
        int r = idx >> 4, j = idx & 15;
        float4 val = make_float4(0.f, 0.f, 0.f, 0.f);
        if (row0 + r < n) val = in4[(size_t)(row0 + r) * 16 + j];
        ((float4*)sIn)[r * 17 + j] = val;
    }
    __syncthreads();

    int c4 = (tid & 15) * 4;
    int rl = (tid >> 4) * 4;
    float acc[4][4] = {{0.f}};
#pragma unroll 8
    for (int k = 0; k < 64; ++k) {
        float4 wv = *(const float4*)(sW + k * 64 + c4);
        float a0 = sIn[(rl + 0) * 68 + k];
        float a1 = sIn[(rl + 1) * 68 + k];
        float a2 = sIn[(rl + 2) * 68 + k];
        float a3 = sIn[(rl + 3) * 68 + k];
        acc[0][0] += a0 * wv.x; acc[0][1] += a0 * wv.y; acc[0][2] += a0 * wv.z; acc[0][3] += a0 * wv.w;
        acc[1][0] += a1 * wv.x; acc[1][1] += a1 * wv.y; acc[1][2] += a1 * wv.z; acc[1][3] += a1 * wv.w;
        acc[2][0] += a2 * wv.x; acc[2][1] += a2 * wv.y; acc[2][2] += a2 * wv.z; acc[2][3] += a2 * wv.w;
        acc[3][0] += a3 * wv.x; acc[3][1] += a3 * wv.y; acc[3][2] += a3 * wv.z; acc[3][3] += a3 * wv.w;
    }

    float scl[4], shf[4];
#pragma unroll
    for (int j = 0; j < 4; ++j) {
        int c = c4 + j;
        float bsum = bias ? bias[c] : 0.0f;
        if (mode == 1) {
            float sc = bn_g[c] * rsqrtf(bn_v[c] + 1e-5f);
            scl[j] = sc;
            shf[j] = bn_b[c] - bn_m[c] * sc + bsum * sc;
        } else {
            scl[j] = 1.0f;
            shf[j] = bsum;
        }
    }
#pragma unroll
    for (int r = 0; r < 4; ++r) {
        int row = row0 + rl + r;
        if (row < n) {
            float4 o;
            o.x = acc[r][0] * scl[0] + shf[0];
            o.y = acc[r][1] * scl[1] + shf[1];
            o.z = acc[r][2] * scl[2] + shf[2];
            o.w = acc[r][3] * scl[3] + shf[3];
            if (mode == 1) {
                o.x = fmaxf(o.x, 0.f); o.y = fmaxf(o.y, 0.f);
                o.z = fmaxf(o.z, 0.f); o.w = fmaxf(o.w, 0.f);
            }
            *(float4*)(out + (size_t)row * 64 + c4) = o;
        }
    }
}

extern "C" void kernel_launch(void* const* d_in, const int* in_sizes, int n_in,
                              void* d_out, int out_size, void* d_ws, size_t ws_size,
                              hipStream_t stream) {
    const float* x      = (const float*)d_in[0];
    const float* lin_W  = (const float*)d_in[1];
    const float* lin_b  = (const float*)d_in[2];
    const float* eps    = (const float*)d_in[3];
    const float* gin_W1 = (const float*)d_in[4];
    const float* gin_b1 = (const float*)d_in[5];
    const float* gbn_g  = (const float*)d_in[6];
    const float* gbn_b  = (const float*)d_in[7];
    const float* gbn_m  = (const float*)d_in[8];
    const float* gbn_v  = (const float*)d_in[9];
    const float* gin_W2 = (const float*)d_in[10];
    const float* gin_b2 = (const float*)d_in[11];
    const float* bn_g   = (const float*)d_in[12];
    const float* bn_b   = (const float*)d_in[13];
    const float* bn_m   = (const float*)d_in[14];
    const float* bn_v   = (const float*)d_in[15];
    const float* vn_emb = (const float*)d_in[16];
    const float* vn_W1  = (const float*)d_in[17];
    const float* vn_b1  = (const float*)d_in[18];
    const float* v1g    = (const float*)d_in[19];
    const float* v1b    = (const float*)d_in[20];
    const float* v1m    = (const float*)d_in[21];
    const float* v1v    = (const float*)d_in[22];
    const float* vn_W2  = (const float*)d_in[23];
    const float* vn_b2  = (const float*)d_in[24];
    const float* v2g    = (const float*)d_in[25];
    const float* v2b    = (const float*)d_in[26];
    const float* v2m    = (const float*)d_in[27];
    const float* v2v    = (const float*)d_in[28];
    const int* src      = (const int*)d_in[29];
    const int* dst      = (const int*)d_in[30];
    const int* batch_id = (const int*)d_in[31];
    float* out = (float*)d_out;

    // workspace layout (floats first, then ints; all 16B aligned)
    float* h      = (float*)d_ws;                      // N*64
    float* agg    = h   + (size_t)N_NODES * 64;        // N*64
    float* z1     = agg + (size_t)N_NODES * 64;        // N*64 (aliased: rbuf / z1 / vt — disjoint lifetimes)
    float* vn     = z1  + (size_t)N_NODES * 64;        // B*64
    float* pooled = vn  + (size_t)NB * 64;             // B*64
    int*   deg     = (int*)(pooled + (size_t)NB * 64); // N (also cursor after scan)
    int*   row_ptr = deg + N_NODES;                    // N+1
    int*   cursor  = row_ptr + N_NODES + 1;            // N
    int*   csr_src = cursor + N_NODES + 1;             // E
    float* rbuf = z1;

    const int GB = (N_NODES + 63) / 64;                // 782
    const int PRE_BLOCKS  = N_NODES * 16 / 256;        // 3125 (exact)
    const int EDGE_BLOCKS = N_EDGES / 256;             // 6250 (exact)
    const int AGG_BLOCKS  = N_NODES / 4;               // 12500 (exact)

    // ---- CSR build (once per launch) ----
    hipMemsetAsync(deg, 0, N_NODES * sizeof(int), stream);
    k_hist<<<EDGE_BLOCKS, 256, 0, stream>>>(dst, deg);
    k_scan<<<1, 1024, 0, stream>>>(deg, row_ptr, cursor);
    k_scatter<<<EDGE_BLOCKS, 256, 0, stream>>>(src, dst, cursor, csr_src);

    // input linear: h = x @ lin_W + lin_b
    k_gemm<<<GB, 256, 0, stream>>>(x, lin_W, lin_b, nullptr, nullptr, nullptr,
                                   nullptr, h, N_NODES, 0);
    k_vn_init<<<32, 256, 0, stream>>>(vn_emb, vn);

    for (int l = 0; l < 4; ++l) {   // layer 4's GINConv output (h_list[5]) is never used
        // h += vn[batch]; out accumulate; rbuf = relu(h)
        k_pre<<<PRE_BLOCKS, 256, 0, stream>>>(h, vn, batch_id, out, rbuf, l == 0);
        // pooled = segment_sum(h, batch) + vn
        k_pool<<<NB, 64, 0, stream>>>(h, batch_id, vn, pooled, N_NODES);
        // agg = (1+eps)*h + CSR-gather-sum of rbuf
        k_agg<<<AGG_BLOCKS, 256, 0, stream>>>(h, rbuf, row_ptr, csr_src, agg, eps, l);
        // z1 = relu(BN1(agg @ W1 + b1))   (z1 aliases rbuf — rbuf dead after k_agg)
        k_gemm<<<GB, 256, 0, stream>>>(agg, gin_W1 + l * 4096, gin_b1 + l * 64,
                                       gbn_g + l * 64, gbn_b + l * 64,
                                       gbn_m + l * 64, gbn_v + l * 64, z1, N_NODES, 1);
        // h = BN2(z1 @ W2 + b2) with relu (l<4 always here)
        k_gemm<<<GB, 256, 0, stream>>>(z1, gin_W2 + l * 4096, gin_b2 + l * 64,
                                       bn_g + l * 64, bn_b + l * 64,
                                       bn_m + l * 64, bn_v + l * 64, h, N_NODES, 1);
        // vn MLP
        k_gemm<<<2, 256, 0, stream>>>(pooled, vn_W1 + l * 4096, vn_b1 + l * 64,
                                      v1g + l * 64, v1b + l * 64,
                                      v1m + l * 64, v1v + l * 64, z1, NB, 1);
        k_gemm<<<2, 256, 0, stream>>>(z1, vn_W2 + l * 4096, vn_b2 + l * 64,
                                      v2g + l * 64, v2b + l * 64,
                                      v2m + l * 64, v2v + l * 64, vn, NB, 1);
    }
    // l = 4: only h += vn[batch]; out += h
    k_pre<<<PRE_BLOCKS, 256, 0, stream>>>(h, vn, batch_id, out, nullptr, 0);
}

// Round 3
// 789.989 us; speedup vs baseline: 7.5404x; 1.6264x over previous
//
#include <hip/hip_runtime.h>

#define N_NODES 50000
#define N_EDGES 1600000
#define NB 128

__device__ __forceinline__ unsigned short f2bf(float f) {
    unsigned u = __float_as_uint(f);
    unsigned r = (u + 0x7FFFu + ((u >> 16) & 1u)) >> 16;   // RNE
    return (unsigned short)r;
}
__device__ __forceinline__ float bf2f(unsigned short u) {
    return __uint_as_float(((unsigned)u) << 16);
}

// ---- CSR build (per launch; edges are launch-constant) ----
__global__ __launch_bounds__(256) void k_hist(
    const int* __restrict__ dst, int* __restrict__ deg) {
    int e = blockIdx.x * 256 + threadIdx.x;
    atomicAdd(&deg[dst[e]], 1);
}

// single block, 1024 threads: exclusive scan of deg -> row_ptr, cursor
__global__ __launch_bounds__(1024) void k_scan(
    const int* __restrict__ deg, int* __restrict__ row_ptr, int* __restrict__ cursor) {
    __shared__ int lsum[1024];
    const int CH = 49;   // 1024*49 >= N
    int t = threadIdx.x;
    int begin = t * CH;
    int end = begin + CH; if (end > N_NODES) end = N_NODES;
    int s = 0;
    for (int i = begin; i < end; ++i) s += deg[i];
    lsum[t] = s;
    __syncthreads();
    for (int off = 1; off < 1024; off <<= 1) {
        int x = lsum[t];
        int y = (t >= off) ? lsum[t - off] : 0;
        __syncthreads();
        lsum[t] = x + y;
        __syncthreads();
    }
    int run = lsum[t] - s;
    for (int i = begin; i < end; ++i) {
        row_ptr[i] = run; cursor[i] = run; run += deg[i];
    }
    if (t == 1023) row_ptr[N_NODES] = lsum[1023];
}

// 4 dst-range sub-passes (blockIdx.y) keep csr writes L2-resident
__global__ __launch_bounds__(256) void k_scatter(
    const int* __restrict__ src, const int* __restrict__ dst,
    int* __restrict__ cursor, unsigned short* __restrict__ csr_src) {
    int e = blockIdx.x * 256 + threadIdx.x;
    int d = dst[e];
    if ((d >> 14) != (int)blockIdx.y) return;
    int pos = atomicAdd(&cursor[d], 1);
    csr_src[pos] = (unsigned short)src[e];
}

__global__ __launch_bounds__(256) void k_vn_init(
    const float* __restrict__ vn_emb, float* __restrict__ vn) {
    int t = blockIdx.x * 256 + threadIdx.x;
    vn[t] = vn_emb[t & 63];
}

// pooled = vn  (init before k_pre's atomic accumulation)
__global__ __launch_bounds__(256) void k_cp_pool(
    const float* __restrict__ vn, float* __restrict__ pooled) {
    int t = blockIdx.x * 256 + threadIdx.x;
    pooled[t] = vn[t];
}

// Fused: h += vn[batch]; out (init/accum); rbuf = bf16(relu(h)); pooled += seg_sum(h)
// wave handles 16 consecutive rows; lane: group g=lane>>4 (row within quad), c4=(lane&15)*4
__global__ __launch_bounds__(256) void k_pre(
    float* __restrict__ h, const float* __restrict__ vn,
    const int* __restrict__ batch_id, float* __restrict__ out,
    unsigned short* __restrict__ rbuf, float* __restrict__ pooled, int first) {
    int wave = threadIdx.x >> 6, lane = threadIdx.x & 63;
    int r0 = blockIdx.x * 64 + wave * 16;
    if (r0 >= N_NODES) return;
    int g = lane >> 4;
    int c4 = (lane & 15) * 4;
    bool full = (r0 + 15 < N_NODES);
    bool fast = full && (batch_id[r0] == batch_id[r0 + 15]);
    float4 pacc = make_float4(0.f, 0.f, 0.f, 0.f);
#pragma unroll
    for (int i = 0; i < 4; ++i) {
        int row = r0 + i * 4 + g;
        if (row >= N_NODES) continue;
        int b = batch_id[row];
        float4 hv = *(const float4*)(h + (size_t)row * 64 + c4);
        float4 vv = *(const float4*)(vn + b * 64 + c4);
        float4 v;
        v.x = hv.x + vv.x; v.y = hv.y + vv.y; v.z = hv.z + vv.z; v.w = hv.w + vv.w;
        *(float4*)(h + (size_t)row * 64 + c4) = v;
        if (first) {
            *(float4*)(out + (size_t)row * 64 + c4) = v;
        } else {
            float4 o = *(const float4*)(out + (size_t)row * 64 + c4);
            o.x += v.x; o.y += v.y; o.z += v.z; o.w += v.w;
            *(float4*)(out + (size_t)row * 64 + c4) = o;
        }
        if (rbuf) {
            ushort4 rb;
            rb.x = f2bf(fmaxf(v.x, 0.f)); rb.y = f2bf(fmaxf(v.y, 0.f));
            rb.z = f2bf(fmaxf(v.z, 0.f)); rb.w = f2bf(fmaxf(v.w, 0.f));
            *(ushort4*)(rbuf + (size_t)row * 64 + c4) = rb;
        }
        if (pooled) {
            if (fast) {
                pacc.x += v.x; pacc.y += v.y; pacc.z += v.z; pacc.w += v.w;
            } else {
                atomicAdd(&pooled[b * 64 + c4 + 0], v.x);
                atomicAdd(&pooled[b * 64 + c4 + 1], v.y);
                atomicAdd(&pooled[b * 64 + c4 + 2], v.z);
                atomicAdd(&pooled[b * 64 + c4 + 3], v.w);
            }
        }
    }
    if (pooled && fast) {
        pacc.x += __shfl_xor(pacc.x, 16); pacc.x += __shfl_xor(pacc.x, 32);
        pacc.y += __shfl_xor(pacc.y, 16); pacc.y += __shfl_xor(pacc.y, 32);
        pacc.z += __shfl_xor(pacc.z, 16); pacc.z += __shfl_xor(pacc.z, 32);
        pacc.w += __shfl_xor(pacc.w, 16); pacc.w += __shfl_xor(pacc.w, 32);
        if (g == 0) {
            int b = batch_id[r0];
            atomicAdd(&pooled[b * 64 + c4 + 0], pacc.x);
            atomicAdd(&pooled[b * 64 + c4 + 1], pacc.y);
            atomicAdd(&pooled[b * 64 + c4 + 2], pacc.z);
            atomicAdd(&pooled[b * 64 + c4 + 3], pacc.w);
        }
    }
}

// agg[d] = (1+eps[l])*h[d] + sum over csr row of bf16 rbuf[src]
// one wave per dst node (lane = channel); 4 waves/block
__global__ __launch_bounds__(256) void k_agg(
    const float* __restrict__ h, const unsigned short* __restrict__ rbuf,
    const int* __restrict__ row_ptr, const unsigned short* __restrict__ csr_src,
    float* __restrict__ agg, const float* __restrict__ eps, int l) {
    int wave = threadIdx.x >> 6;
    int lane = threadIdx.x & 63;
    int node = blockIdx.x * 4 + wave;
    int start = row_ptr[node], end = row_ptr[node + 1];
    float acc = (1.0f + eps[l]) * h[(size_t)node * 64 + lane];
    for (int base = start; base < end; base += 64) {
        int e = base + lane;
        int s = (e < end) ? (int)csr_src[e] : 0;
        int cnt = end - base; if (cnt > 64) cnt = 64;
        int j = 0;
        for (; j + 3 < cnt; j += 4) {
            int s0 = __shfl(s, j), s1 = __shfl(s, j + 1);
            int s2 = __shfl(s, j + 2), s3 = __shfl(s, j + 3);
            float v0 = bf2f(rbuf[(size_t)s0 * 64 + lane]);
            float v1 = bf2f(rbuf[(size_t)s1 * 64 + lane]);
            float v2 = bf2f(rbuf[(size_t)s2 * 64 + lane]);
            float v3 = bf2f(rbuf[(size_t)s3 * 64 + lane]);
            acc += (v0 + v1) + (v2 + v3);
        }
        for (; j < cnt; ++j) {
            int sj = __shfl(s, j);
            acc += bf2f(rbuf[(size_t)sj * 64 + lane]);
        }
    }
    agg[(size_t)node * 64 + lane] = acc;
}

// out = op(in @ W + bias); mode 0: bias only; mode 1: bias + BN + relu
__global__ __launch_bounds__(256) void k_gemm(
    const float* __restrict__ in, const float* __restrict__ W,
    const float* __restrict__ bias, const float* __restrict__ bn_g,
    const float* __restrict__ bn_b, const float* __restrict__ bn_m,
    const float* __restrict__ bn_v, float* __restrict__ out, int n, int mode) {
    __shared__ float sW[64 * 64];
    __shared__ float sIn[64 * 68];
    int tid = threadIdx.x;
    int row0 = blockIdx.x * 64;

    const float4* W4 = (const float4*)W;
    float4* sW4 = (float4*)sW;
#pragma unroll
    for (int i = 0; i < 4; ++i) sW4[tid + 256 * i] = W4[tid + 256 * i];

    const float4* in4 = (const float4*)in;
#pragma unroll
    for (int i = 0; i < 4; ++i) {
        int idx = tid + 256 * i;
        int r = idx >> 4, j = idx & 15;
        float4 val = make_float4(0.f, 0.f, 0.f, 0.f);
        if (row0 + r < n) val = in4[(size_t)(row0 + r) * 16 + j];
        ((float4*)sIn)[r * 17 + j] = val;
    }
    __syncthreads();

    int c4 = (tid & 15) * 4;
    int rl = (tid >> 4) * 4;
    float acc[4][4] = {{0.f}};
#pragma unroll 8
    for (int k = 0; k < 64; ++k) {
        float4 wv = *(const float4*)(sW + k * 64 + c4);
        float a0 = sIn[(rl + 0) * 68 + k];
        float a1 = sIn[(rl + 1) * 68 + k];
        float a2 = sIn[(rl + 2) * 68 + k];
        float a3 = sIn[(rl + 3) * 68 + k];
        acc[0][0] += a0 * wv.x; acc[0][1] += a0 * wv.y; acc[0][2] += a0 * wv.z; acc[0][3] += a0 * wv.w;
        acc[1][0] += a1 * wv.x; acc[1][1] += a1 * wv.y; acc[1][2] += a1 * wv.z; acc[1][3] += a1 * wv.w;
        acc[2][0] += a2 * wv.x; acc[2][1] += a2 * wv.y; acc[2][2] += a2 * wv.z; acc[2][3] += a2 * wv.w;
        acc[3][0] += a3 * wv.x; acc[3][1] += a3 * wv.y; acc[3][2] += a3 * wv.z; acc[3][3] += a3 * wv.w;
    }

    float scl[4], shf[4];
#pragma unroll
    for (int j = 0; j < 4; ++j) {
        int c = c4 + j;
        float bsum = bias ? bias[c] : 0.0f;
        if (mode == 1) {
            float sc = bn_g[c] * rsqrtf(bn_v[c] + 1e-5f);
            scl[j] = sc;
            shf[j] = bn_b[c] - bn_m[c] * sc + bsum * sc;
        } else {
            scl[j] = 1.0f;
            shf[j] = bsum;
        }
    }
#pragma unroll
    for (int r = 0; r < 4; ++r) {
        int row = row0 + rl + r;
        if (row < n) {
            float4 o;
            o.x = acc[r][0] * scl[0] + shf[0];
            o.y = acc[r][1] * scl[1] + shf[1];
            o.z = acc[r][2] * scl[2] + shf[2];
            o.w = acc[r][3] * scl[3] + shf[3];
            if (mode == 1) {
                o.x = fmaxf(o.x, 0.f); o.y = fmaxf(o.y, 0.f);
                o.z = fmaxf(o.z, 0.f); o.w = fmaxf(o.w, 0.f);
            }
            *(float4*)(out + (size_t)row * 64 + c4) = o;
        }
    }
}

extern "C" void kernel_launch(void* const* d_in, const int* in_sizes, int n_in,
                              void* d_out, int out_size, void* d_ws, size_t ws_size,
                              hipStream_t stream) {
    const float* x      = (const float*)d_in[0];
    const float* lin_W  = (const float*)d_in[1];
    const float* lin_b  = (const float*)d_in[2];
    const float* eps    = (const float*)d_in[3];
    const float* gin_W1 = (const float*)d_in[4];
    const float* gin_b1 = (const float*)d_in[5];
    const float* gbn_g  = (const float*)d_in[6];
    const float* gbn_b  = (const float*)d_in[7];
    const float* gbn_m  = (const float*)d_in[8];
    const float* gbn_v  = (const float*)d_in[9];
    const float* gin_W2 = (const float*)d_in[10];
    const float* gin_b2 = (const float*)d_in[11];
    const float* bn_g   = (const float*)d_in[12];
    const float* bn_b   = (const float*)d_in[13];
    const float* bn_m   = (const float*)d_in[14];
    const float* bn_v   = (const float*)d_in[15];
    const float* vn_emb = (const float*)d_in[16];
    const float* vn_W1  = (const float*)d_in[17];
    const float* vn_b1  = (const float*)d_in[18];
    const float* v1g    = (const float*)d_in[19];
    const float* v1b    = (const float*)d_in[20];
    const float* v1m    = (const float*)d_in[21];
    const float* v1v    = (const float*)d_in[22];
    const float* vn_W2  = (const float*)d_in[23];
    const float* vn_b2  = (const float*)d_in[24];
    const float* v2g    = (const float*)d_in[25];
    const float* v2b    = (const float*)d_in[26];
    const float* v2m    = (const float*)d_in[27];
    const float* v2v    = (const float*)d_in[28];
    const int* src      = (const int*)d_in[29];
    const int* dst      = (const int*)d_in[30];
    const int* batch_id = (const int*)d_in[31];
    float* out = (float*)d_out;

    // workspace layout
    float* h      = (float*)d_ws;                      // N*64 f32
    float* agg    = h   + (size_t)N_NODES * 64;        // N*64 f32
    float* z1     = agg + (size_t)N_NODES * 64;        // N*64 f32; rbuf16 aliases its first half
    float* vn     = z1  + (size_t)N_NODES * 64;        // B*64
    float* pooled = vn  + (size_t)NB * 64;             // B*64
    float* vt     = pooled + (size_t)NB * 64;          // B*64
    int*   deg     = (int*)(vt + (size_t)NB * 64);     // N
    int*   row_ptr = deg + N_NODES;                    // N+1
    int*   cursor  = row_ptr + N_NODES + 1;            // N
    unsigned short* csr_src = (unsigned short*)(cursor + N_NODES + 1); // E (ushort)
    unsigned short* rbuf = (unsigned short*)z1;        // N*64 bf16 (alias z1 — disjoint lifetime)

    const int GB = (N_NODES + 63) / 64;                // 782
    const int EDGE_BLOCKS = N_EDGES / 256;             // 6250

    // ---- CSR build ----
    hipMemsetAsync(deg, 0, N_NODES * sizeof(int), stream);
    k_hist<<<EDGE_BLOCKS, 256, 0, stream>>>(dst, deg);
    k_scan<<<1, 1024, 0, stream>>>(deg, row_ptr, cursor);
    k_scatter<<<dim3(EDGE_BLOCKS, 4), 256, 0, stream>>>(src, dst, cursor, csr_src);

    // input linear
    k_gemm<<<GB, 256, 0, stream>>>(x, lin_W, lin_b, nullptr, nullptr, nullptr,
                                   nullptr, h, N_NODES, 0);
    k_vn_init<<<32, 256, 0, stream>>>(vn_emb, vn);

    for (int l = 0; l < 4; ++l) {   // layer 4's GINConv output is never used
        k_cp_pool<<<32, 256, 0, stream>>>(vn, pooled);
        k_pre<<<GB, 256, 0, stream>>>(h, vn, batch_id, out, rbuf, pooled, l == 0);
        k_agg<<<N_NODES / 4, 256, 0, stream>>>(h, rbuf, row_ptr, csr_src, agg, eps, l);
        k_gemm<<<GB, 256, 0, stream>>>(agg, gin_W1 + l * 4096, gin_b1 + l * 64,
                                       gbn_g + l * 64, gbn_b + l * 64,
                                       gbn_m + l * 64, gbn_v + l * 64, z1, N_NODES, 1);
        k_gemm<<<GB, 256, 0, stream>>>(z1, gin_W2 + l * 4096, gin_b2 + l * 64,
                                       bn_g + l * 64, bn_b + l * 64,
                                       bn_m + l * 64, bn_v + l * 64, h, N_NODES, 1);
        k_gemm<<<2, 256, 0, stream>>>(pooled, vn_W1 + l * 4096, vn_b1 + l * 64,
                                      v1g + l * 64, v1b + l * 64,
                                      v1m + l * 64, v1v + l * 64, vt, NB, 1);
        k_gemm<<<2, 256, 0, stream>>>(vt, vn_W2 + l * 4096, vn_b2 + l * 64,
                                      v2g + l * 64, v2b + l * 64,
                                      v2m + l * 64, v2v + l * 64, vn, NB, 1);
    }
    // l = 4: only h += vn[batch]; out += h
    k_pre<<<GB, 256, 0, stream>>>(h, vn, batch_id, out, nullptr, nullptr, 0);
}

// Round 4
// 674.752 us; speedup vs baseline: 8.8282x; 1.1708x over previous
//
#include <hip/hip_runtime.h>

#define N_NODES 50000
#define N_EDGES 1600000
#define NB 128
#define NBLK 196   // ceil(N/256)

__device__ __forceinline__ unsigned short f2bf(float f) {
    unsigned u = __float_as_uint(f);
    unsigned r = (u + 0x7FFFu + ((u >> 16) & 1u)) >> 16;   // RNE
    return (unsigned short)r;
}
__device__ __forceinline__ float bf2f(unsigned short u) {
    return __uint_as_float(((unsigned)u) << 16);
}

// ---- CSR build (per launch; edges are launch-constant) ----
__global__ __launch_bounds__(256) void k_hist(
    const int* __restrict__ dst, int* __restrict__ deg) {
    int e = blockIdx.x * 256 + threadIdx.x;
    atomicAdd(&deg[dst[e]], 1);
}

// phase A: per-block (256-elem) sums of deg
__global__ __launch_bounds__(256) void k_scan_part(
    const int* __restrict__ deg, int* __restrict__ bsum) {
    int i = blockIdx.x * 256 + threadIdx.x;
    int v = (i < N_NODES) ? deg[i] : 0;
#pragma unroll
    for (int off = 1; off < 64; off <<= 1) v += __shfl_xor(v, off);
    __shared__ int ws[4];
    if ((threadIdx.x & 63) == 0) ws[threadIdx.x >> 6] = v;
    __syncthreads();
    if (threadIdx.x == 0) bsum[blockIdx.x] = ws[0] + ws[1] + ws[2] + ws[3];
}

// phase B: single block scans the NBLK block sums -> exclusive boff; writes row_ptr[N]
__global__ __launch_bounds__(256) void k_scan_mid(
    const int* __restrict__ bsum, int* __restrict__ boff, int* __restrict__ row_ptr) {
    __shared__ int s[256];
    int t = threadIdx.x;
    int v = (t < NBLK) ? bsum[t] : 0;
    s[t] = v;
    __syncthreads();
#pragma unroll
    for (int off = 1; off < 256; off <<= 1) {
        int x = s[t];
        int y = (t >= off) ? s[t - off] : 0;
        __syncthreads();
        s[t] = x + y;
        __syncthreads();
    }
    boff[t] = s[t] - v;
    if (t == 255) row_ptr[N_NODES] = s[255];
}

// phase C: per-block exclusive scan + block offset -> row_ptr, cursor
__global__ __launch_bounds__(256) void k_scan_fill(
    const int* __restrict__ deg, const int* __restrict__ boff,
    int* __restrict__ row_ptr, int* __restrict__ cursor) {
    __shared__ int s[256];
    int t = threadIdx.x;
    int i = blockIdx.x * 256 + t;
    int v = (i < N_NODES) ? deg[i] : 0;
    s[t] = v;
    __syncthreads();
#pragma unroll
    for (int off = 1; off < 256; off <<= 1) {
        int x = s[t];
        int y = (t >= off) ? s[t - off] : 0;
        __syncthreads();
        s[t] = x + y;
        __syncthreads();
    }
    if (i < N_NODES) {
        int e = s[t] - v + boff[blockIdx.x];
        row_ptr[i] = e;
        cursor[i] = e;
    }
}

// 4 dst-range sub-passes (blockIdx.y) keep csr writes L2-resident
__global__ __launch_bounds__(256) void k_scatter(
    const int* __restrict__ src, const int* __restrict__ dst,
    int* __restrict__ cursor, unsigned short* __restrict__ csr_src) {
    int e = blockIdx.x * 256 + threadIdx.x;
    int d = dst[e];
    if ((d >> 14) != (int)blockIdx.y) return;
    int pos = atomicAdd(&cursor[d], 1);
    csr_src[pos] = (unsigned short)src[e];
}

// vn = pooled = broadcast(vn_emb)
__global__ __launch_bounds__(256) void k_vn_init(
    const float* __restrict__ vn_emb, float* __restrict__ vn,
    float* __restrict__ pooled) {
    int t = blockIdx.x * 256 + threadIdx.x;
    float v = vn_emb[t & 63];
    vn[t] = v;
    pooled[t] = v;
}

// Fused: h += vn[batch]; out (init/accum); rbuf = bf16(relu(h)); pooled += seg_sum(h)
__global__ __launch_bounds__(256) void k_pre(
    float* __restrict__ h, const float* __restrict__ vn,
    const int* __restrict__ batch_id, float* __restrict__ out,
    unsigned short* __restrict__ rbuf, float* __restrict__ pooled, int first) {
    int wave = threadIdx.x >> 6, lane = threadIdx.x & 63;
    int r0 = blockIdx.x * 64 + wave * 16;
    if (r0 >= N_NODES) return;
    int g = lane >> 4;
    int c4 = (lane & 15) * 4;
    bool full = (r0 + 15 < N_NODES);
    bool fast = full && (batch_id[r0] == batch_id[r0 + 15]);
    float4 pacc = make_float4(0.f, 0.f, 0.f, 0.f);
#pragma unroll
    for (int i = 0; i < 4; ++i) {
        int row = r0 + i * 4 + g;
        if (row >= N_NODES) continue;
        int b = batch_id[row];
        float4 hv = *(const float4*)(h + (size_t)row * 64 + c4);
        float4 vv = *(const float4*)(vn + b * 64 + c4);
        float4 v;
        v.x = hv.x + vv.x; v.y = hv.y + vv.y; v.z = hv.z + vv.z; v.w = hv.w + vv.w;
        *(float4*)(h + (size_t)row * 64 + c4) = v;
        if (first) {
            *(float4*)(out + (size_t)row * 64 + c4) = v;
        } else {
            float4 o = *(const float4*)(out + (size_t)row * 64 + c4);
            o.x += v.x; o.y += v.y; o.z += v.z; o.w += v.w;
            *(float4*)(out + (size_t)row * 64 + c4) = o;
        }
        if (rbuf) {
            ushort4 rb;
            rb.x = f2bf(fmaxf(v.x, 0.f)); rb.y = f2bf(fmaxf(v.y, 0.f));
            rb.z = f2bf(fmaxf(v.z, 0.f)); rb.w = f2bf(fmaxf(v.w, 0.f));
            *(ushort4*)(rbuf + (size_t)row * 64 + c4) = rb;
        }
        if (pooled) {
            if (fast) {
                pacc.x += v.x; pacc.y += v.y; pacc.z += v.z; pacc.w += v.w;
            } else {
                atomicAdd(&pooled[b * 64 + c4 + 0], v.x);
                atomicAdd(&pooled[b * 64 + c4 + 1], v.y);
                atomicAdd(&pooled[b * 64 + c4 + 2], v.z);
                atomicAdd(&pooled[b * 64 + c4 + 3], v.w);
            }
        }
    }
    if (pooled && fast) {
        pacc.x += __shfl_xor(pacc.x, 16); pacc.x += __shfl_xor(pacc.x, 32);
        pacc.y += __shfl_xor(pacc.y, 16); pacc.y += __shfl_xor(pacc.y, 32);
        pacc.z += __shfl_xor(pacc.z, 16); pacc.z += __shfl_xor(pacc.z, 32);
        pacc.w += __shfl_xor(pacc.w, 16); pacc.w += __shfl_xor(pacc.w, 32);
        if (g == 0) {
            int b = batch_id[r0];
            atomicAdd(&pooled[b * 64 + c4 + 0], pacc.x);
            atomicAdd(&pooled[b * 64 + c4 + 1], pacc.y);
            atomicAdd(&pooled[b * 64 + c4 + 2], pacc.z);
            atomicAdd(&pooled[b * 64 + c4 + 3], pacc.w);
        }
    }
}

// agg[d] = (1+eps[l])*h[d] + sum over csr row of bf16 rbuf[src]
__global__ __launch_bounds__(256) void k_agg(
    const float* __restrict__ h, const unsigned short* __restrict__ rbuf,
    const int* __restrict__ row_ptr, const unsigned short* __restrict__ csr_src,
    float* __restrict__ agg, const float* __restrict__ eps, int l) {
    int wave = threadIdx.x >> 6;
    int lane = threadIdx.x & 63;
    int node = blockIdx.x * 4 + wave;
    int start = row_ptr[node], end = row_ptr[node + 1];
    float acc = (1.0f + eps[l]) * h[(size_t)node * 64 + lane];
    for (int base = start; base < end; base += 64) {
        int e = base + lane;
        int s = (e < end) ? (int)csr_src[e] : 0;
        int cnt = end - base; if (cnt > 64) cnt = 64;
        int j = 0;
        for (; j + 3 < cnt; j += 4) {
            int s0 = __shfl(s, j), s1 = __shfl(s, j + 1);
            int s2 = __shfl(s, j + 2), s3 = __shfl(s, j + 3);
            float v0 = bf2f(rbuf[(size_t)s0 * 64 + lane]);
            float v1 = bf2f(rbuf[(size_t)s1 * 64 + lane]);
            float v2 = bf2f(rbuf[(size_t)s2 * 64 + lane]);
            float v3 = bf2f(rbuf[(size_t)s3 * 64 + lane]);
            acc += (v0 + v1) + (v2 + v3);
        }
        for (; j < cnt; ++j) {
            int sj = __shfl(s, j);
            acc += bf2f(rbuf[(size_t)sj * 64 + lane]);
        }
    }
    agg[(size_t)node * 64 + lane] = acc;
}

// out = op(in @ W + bias); mode 0: bias only; mode 1: bias + BN + relu
__global__ __launch_bounds__(256) void k_gemm(
    const float* __restrict__ in, const float* __restrict__ W,
    const float* __restrict__ bias, const float* __restrict__ bn_g,
    const float* __restrict__ bn_b, const float* __restrict__ bn_m,
    const float* __restrict__ bn_v, float* __restrict__ out, int n, int mode) {
    __shared__ float sW[64 * 64];
    __shared__ float sIn[64 * 68];
    int tid = threadIdx.x;
    int row0 = blockIdx.x * 64;

    const float4* W4 = (const float4*)W;
    float4* sW4 = (float4*)sW;
#pragma unroll
    for (int i = 0; i < 4; ++i) sW4[tid + 256 * i] = W4[tid + 256 * i];

    const float4* in4 = (const float4*)in;
#pragma unroll
    for (int i = 0; i < 4; ++i) {
        int idx = tid + 256 * i;
        int r = idx >> 4, j = idx & 15;
        float4 val = make_float4(0.f, 0.f, 0.f, 0.f);
        if (row0 + r < n) val = in4[(size_t)(row0 + r) * 16 + j];
        ((float4*)sIn)[r * 17 + j] = val;
    }
    __syncthreads();

    int c4 = (tid & 15) * 4;
    int rl = (tid >> 4) * 4;
    float acc[4][4] = {{0.f}};
#pragma unroll 8
    for (int k = 0; k < 64; ++k) {
        float4 wv = *(const float4*)(sW + k * 64 + c4);
        float a0 = sIn[(rl + 0) * 68 + k];
        float a1 = sIn[(rl + 1) * 68 + k];
        float a2 = sIn[(rl + 2) * 68 + k];
        float a3 = sIn[(rl + 3) * 68 + k];
        acc[0][0] += a0 * wv.x; acc[0][1] += a0 * wv.y; acc[0][2] += a0 * wv.z; acc[0][3] += a0 * wv.w;
        acc[1][0] += a1 * wv.x; acc[1][1] += a1 * wv.y; acc[1][2] += a1 * wv.z; acc[1][3] += a1 * wv.w;
        acc[2][0] += a2 * wv.x; acc[2][1] += a2 * wv.y; acc[2][2] += a2 * wv.z; acc[2][3] += a2 * wv.w;
        acc[3][0] += a3 * wv.x; acc[3][1] += a3 * wv.y; acc[3][2] += a3 * wv.z; acc[3][3] += a3 * wv.w;
    }

    float scl[4], shf[4];
#pragma unroll
    for (int j = 0; j < 4; ++j) {
        int c = c4 + j;
        float bsum = bias ? bias[c] : 0.0f;
        if (mode == 1) {
            float sc = bn_g[c] * rsqrtf(bn_v[c] + 1e-5f);
            scl[j] = sc;
            shf[j] = bn_b[c] - bn_m[c] * sc + bsum * sc;
        } else {
            scl[j] = 1.0f;
            shf[j] = bsum;
        }
    }
#pragma unroll
    for (int r = 0; r < 4; ++r) {
        int row = row0 + rl + r;
        if (row < n) {
            float4 o;
            o.x = acc[r][0] * scl[0] + shf[0];
            o.y = acc[r][1] * scl[1] + shf[1];
            o.z = acc[r][2] * scl[2] + shf[2];
            o.w = acc[r][3] * scl[3] + shf[3];
            if (mode == 1) {
                o.x = fmaxf(o.x, 0.f); o.y = fmaxf(o.y, 0.f);
                o.z = fmaxf(o.z, 0.f); o.w = fmaxf(o.w, 0.f);
            }
            *(float4*)(out + (size_t)row * 64 + c4) = o;
        }
    }
}

// Fused vn MLP: vn_out = relu(BN2(relu(BN1(pooled @ W1 + b1)) @ W2 + b2))
// single block, 512 threads; also writes pooled_out = vn_out (init for next layer)
__global__ __launch_bounds__(512) void k_vnmlp(
    const float* __restrict__ pooled_in,
    const float* __restrict__ W1, const float* __restrict__ b1,
    const float* __restrict__ g1, const float* __restrict__ be1,
    const float* __restrict__ m1, const float* __restrict__ v1,
    const float* __restrict__ W2, const float* __restrict__ b2,
    const float* __restrict__ g2, const float* __restrict__ be2,
    const float* __restrict__ m2, const float* __restrict__ v2,
    float* __restrict__ vn_out, float* __restrict__ pooled_out) {
    __shared__ float sP[128 * 68];   // padded stride 68
    __shared__ float sW[64 * 64];
    int tid = threadIdx.x;

    // load W1 (4096 floats = 1024 float4; 512 thr x 2)
#pragma unroll
    for (int i = 0; i < 2; ++i)
        ((float4*)sW)[tid + 512 * i] = ((const float4*)W1)[tid + 512 * i];
    // load pooled (8192 floats = 2048 float4; 512 thr x 4), padded rows
#pragma unroll
    for (int i = 0; i < 4; ++i) {
        int idx = tid + 512 * i;
        int r = idx >> 4, j = idx & 15;
        ((float4*)(sP + r * 68))[j] = ((const float4*)pooled_in)[idx];
    }
    __syncthreads();

    int cg = tid & 15, rg = tid >> 4;   // rg: 0..31 -> 4 rows each
    int c4 = cg * 4;
    float acc[4][4] = {{0.f}};
#pragma unroll 8
    for (int k = 0; k < 64; ++k) {
        float4 w = *(const float4*)(sW + k * 64 + c4);
#pragma unroll
        for (int i = 0; i < 4; ++i) {
            float a = sP[(rg * 4 + i) * 68 + k];
            acc[i][0] += a * w.x; acc[i][1] += a * w.y;
            acc[i][2] += a * w.z; acc[i][3] += a * w.w;
        }
    }
    float scl[4], shf[4];
#pragma unroll
    for (int j = 0; j < 4; ++j) {
        int c = c4 + j;
        float sc = g1[c] * rsqrtf(v1[c] + 1e-5f);
        scl[j] = sc;
        shf[j] = be1[c] - m1[c] * sc + b1[c] * sc;
    }
    __syncthreads();   // all stage-1 reads of sP/sW complete
    // write vt into sP; load W2 into sW
#pragma unroll
    for (int i = 0; i < 4; ++i) {
#pragma unroll
        for (int j = 0; j < 4; ++j)
            sP[(rg * 4 + i) * 68 + c4 + j] = fmaxf(acc[i][j] * scl[j] + shf[j], 0.f);
    }
#pragma unroll
    for (int i = 0; i < 2; ++i)
        ((float4*)sW)[tid + 512 * i] = ((const float4*)W2)[tid + 512 * i];
    __syncthreads();

    float acc2[4][4] = {{0.f}};
#pragma unroll 8
    for (int k = 0; k < 64; ++k) {
        float4 w = *(const float4*)(sW + k * 64 + c4);
#pragma unroll
        for (int i = 0; i < 4; ++i) {
            float a = sP[(rg * 4 + i) * 68 + k];
            acc2[i][0] += a * w.x; acc2[i][1] += a * w.y;
            acc2[i][2] += a * w.z; acc2[i][3] += a * w.w;
        }
    }
#pragma unroll
    for (int j = 0; j < 4; ++j) {
        int c = c4 + j;
        float sc = g2[c] * rsqrtf(v2[c] + 1e-5f);
        scl[j] = sc;
        shf[j] = be2[c] - m2[c] * sc + b2[c] * sc;
    }
#pragma unroll
    for (int i = 0; i < 4; ++i) {
        int row = rg * 4 + i;
        float4 o;
        o.x = fmaxf(acc2[i][0] * scl[0] + shf[0], 0.f);
        o.y = fmaxf(acc2[i][1] * scl[1] + shf[1], 0.f);
        o.z = fmaxf(acc2[i][2] * scl[2] + shf[2], 0.f);
        o.w = fmaxf(acc2[i][3] * scl[3] + shf[3], 0.f);
        *(float4*)(vn_out + row * 64 + c4) = o;
        *(float4*)(pooled_out + row * 64 + c4) = o;
    }
}

extern "C" void kernel_launch(void* const* d_in, const int* in_sizes, int n_in,
                              void* d_out, int out_size, void* d_ws, size_t ws_size,
                              hipStream_t stream) {
    const float* x      = (const float*)d_in[0];
    const float* lin_W  = (const float*)d_in[1];
    const float* lin_b  = (const float*)d_in[2];
    const float* eps    = (const float*)d_in[3];
    const float* gin_W1 = (const float*)d_in[4];
    const float* gin_b1 = (const float*)d_in[5];
    const float* gbn_g  = (const float*)d_in[6];
    const float* gbn_b  = (const float*)d_in[7];
    const float* gbn_m  = (const float*)d_in[8];
    const float* gbn_v  = (const float*)d_in[9];
    const float* gin_W2 = (const float*)d_in[10];
    const float* gin_b2 = (const float*)d_in[11];
    const float* bn_g   = (const float*)d_in[12];
    const float* bn_b   = (const float*)d_in[13];
    const float* bn_m   = (const float*)d_in[14];
    const float* bn_v   = (const float*)d_in[15];
    const float* vn_emb = (const float*)d_in[16];
    const float* vn_W1  = (const float*)d_in[17];
    const float* vn_b1  = (const float*)d_in[18];
    const float* v1g    = (const float*)d_in[19];
    const float* v1b    = (const float*)d_in[20];
    const float* v1m    = (const float*)d_in[21];
    const float* v1v    = (const float*)d_in[22];
    const float* vn_W2  = (const float*)d_in[23];
    const float* vn_b2  = (const float*)d_in[24];
    const float* v2g    = (const float*)d_in[25];
    const float* v2b    = (const float*)d_in[26];
    const float* v2m    = (const float*)d_in[27];
    const float* v2v    = (const float*)d_in[28];
    const int* src      = (const int*)d_in[29];
    const int* dst      = (const int*)d_in[30];
    const int* batch_id = (const int*)d_in[31];
    float* out = (float*)d_out;

    // workspace layout
    float* h      = (float*)d_ws;                      // N*64 f32
    float* agg    = h   + (size_t)N_NODES * 64;        // N*64 f32
    float* z1     = agg + (size_t)N_NODES * 64;        // N*64 f32; rbuf16 aliases first half
    float* vn     = z1  + (size_t)N_NODES * 64;        // B*64
    float* pooled = vn  + (size_t)NB * 64;             // B*64
    int*   deg     = (int*)(pooled + (size_t)NB * 64); // N
    int*   row_ptr = deg + N_NODES;                    // N+1
    int*   cursor  = row_ptr + N_NODES + 1;            // N
    int*   bsum    = cursor + N_NODES;                 // 256
    int*   boff    = bsum + 256;                       // 256
    unsigned short* csr_src = (unsigned short*)(boff + 256); // E (ushort)
    unsigned short* rbuf = (unsigned short*)z1;        // N*64 bf16 (alias z1)

    const int GB = (N_NODES + 63) / 64;                // 782
    const int EDGE_BLOCKS = N_EDGES / 256;             // 6250

    // ---- CSR build ----
    hipMemsetAsync(deg, 0, N_NODES * sizeof(int), stream);
    k_hist<<<EDGE_BLOCKS, 256, 0, stream>>>(dst, deg);
    k_scan_part<<<NBLK, 256, 0, stream>>>(deg, bsum);
    k_scan_mid<<<1, 256, 0, stream>>>(bsum, boff, row_ptr);
    k_scan_fill<<<NBLK, 256, 0, stream>>>(deg, boff, row_ptr, cursor);
    k_scatter<<<dim3(EDGE_BLOCKS, 4), 256, 0, stream>>>(src, dst, cursor, csr_src);

    // input linear + vn/pooled init
    k_gemm<<<GB, 256, 0, stream>>>(x, lin_W, lin_b, nullptr, nullptr, nullptr,
                                   nullptr, h, N_NODES, 0);
    k_vn_init<<<32, 256, 0, stream>>>(vn_emb, vn, pooled);

    for (int l = 0; l < 4; ++l) {   // layer 4's GINConv output is never used
        k_pre<<<GB, 256, 0, stream>>>(h, vn, batch_id, out, rbuf, pooled, l == 0);
        k_agg<<<N_NODES / 4, 256, 0, stream>>>(h, rbuf, row_ptr, csr_src, agg, eps, l);
        k_gemm<<<GB, 256, 0, stream>>>(agg, gin_W1 + l * 4096, gin_b1 + l * 64,
                                       gbn_g + l * 64, gbn_b + l * 64,
                                       gbn_m + l * 64, gbn_v + l * 64, z1, N_NODES, 1);
        k_gemm<<<GB, 256, 0, stream>>>(z1, gin_W2 + l * 4096, gin_b2 + l * 64,
                                       bn_g + l * 64, bn_b + l * 64,
                                       bn_m + l * 64, bn_v + l * 64, h, N_NODES, 1);
        // fused vn MLP; writes vn and pooled-init for next layer
        k_vnmlp<<<1, 512, 0, stream>>>(pooled,
                                       vn_W1 + l * 4096, vn_b1 + l * 64,
                                       v1g + l * 64, v1b + l * 64, v1m + l * 64, v1v + l * 64,
                                       vn_W2 + l * 4096, vn_b2 + l * 64,
                                       v2g + l * 64, v2b + l * 64, v2m + l * 64, v2v + l * 64,
                                       vn, pooled);
    }
    // l = 4: only h += vn[batch]; out += h
    k_pre<<<GB, 256, 0, stream>>>(h, vn, batch_id, out, nullptr, nullptr, 0);
}